// Round 2
// baseline (2825.619 us; speedup 1.0000x reference)
//
#include <hip/hip_runtime.h>
#include <stdint.h>

typedef __bf16 bf16;
typedef __bf16 bf16x4 __attribute__((ext_vector_type(4)));
typedef __bf16 bf16x8 __attribute__((ext_vector_type(8)));
typedef float f32x4 __attribute__((ext_vector_type(4)));

#define MFMA16x16x32(A, B, C) __builtin_amdgcn_mfma_f32_16x16x32_bf16((A), (B), (C), 0, 0, 0)

#define B_ 512
#define T_ 100
#define F_ 1024
#define H_ 1024
#define C_ 10
#define TC_ 10  // T-chunk for XZ staging

__device__ __forceinline__ float sigmoid_f(float x) { return 1.0f / (1.0f + __expf(-x)); }
__device__ __forceinline__ float b2bsqrt_f(float x) {
  float s = sqrtf(1.0f + fabsf(x)) - 1.0f;
  return x >= 0.0f ? s : -s;  // x==0 -> s==0, matches sign(0)=0
}

// ---------------- zero-init h slot 0 and c state (capture-safe) ----------------
__global__ __launch_bounds__(256) void zero_init(bf16* __restrict__ h0,
                                                 float* __restrict__ c0, int n) {
  int i = blockIdx.x * blockDim.x + threadIdx.x;
  if (i < n) { h0[i] = (bf16)0.0f; c0[i] = 0.0f; }
}

// ---------- transpose per gate: fp32 (1024 x 1024) -> bf16 transposed ----------
__global__ __launch_bounds__(256) void tr_kernel(const float* __restrict__ src,
                                                 bf16* __restrict__ dst) {
  __shared__ float tile[32][33];
  int g = blockIdx.z;
  int c0 = blockIdx.x * 32;
  int r0 = blockIdx.y * 32;
  const float* s = src + (size_t)g * 1024 * 1024;
  bf16* d = dst + (size_t)g * 1024 * 1024;
  int tx = threadIdx.x & 31, ty = threadIdx.x >> 5;
  #pragma unroll
  for (int i = 0; i < 32; i += 8)
    tile[ty + i][tx] = s[(size_t)(r0 + ty + i) * 1024 + c0 + tx];
  __syncthreads();
  #pragma unroll
  for (int i = 0; i < 32; i += 8)
    d[(size_t)(c0 + ty + i) * 1024 + r0 + tx] = (bf16)tile[tx][ty + i];
}

// ---------------- xz chunk: XZc = X[:, t0:t0+TC, :] @ W  (bf16 MFMA) ----------------
// X fp32 (B,T,F) row (b*100+t). Wt bf16 (4096,1024), row n=g*1024+h, col k=f.
// out XZc bf16 (TC,4,B,H). Chunk-local row lr in [0, B*TC): b=lr/TC, tt=lr%TC.
__global__ __launch_bounds__(256) void gemm_xz(const float* __restrict__ X,
                                               const bf16* __restrict__ Wt,
                                               bf16* __restrict__ XZc, int t0) {
  __shared__ bf16 sA[128 * 40];  // +8 pad: 80B stride, 16B-aligned, 2-way banks (free)
  __shared__ bf16 sB[128 * 40];
  const int tid = threadIdx.x;
  const int lane = tid & 63;
  const int w = tid >> 6;
  const int l16 = lane & 15;
  const int quad = lane >> 4;
  const int m0 = blockIdx.y * 128;  // chunk-local rows
  const int n0 = blockIdx.x * 128;
  const int wm = (w >> 1) * 64;
  const int wn = (w & 1) * 64;
  const int srow = tid >> 2;       // 0..63
  const int scol = (tid & 3) * 8;  // 0,8,16,24

  // hoist global X row addresses for the 2 staged rows
  size_t grow[2];
  #pragma unroll
  for (int i = 0; i < 2; ++i) {
    unsigned lr = (unsigned)(m0 + srow + i * 64);
    unsigned b = lr / TC_;
    unsigned tt = lr - b * TC_;
    grow[i] = (size_t)(b * 100u + (unsigned)t0 + tt) * 1024;
  }

  f32x4 acc[4][4] = {};

  for (int kk = 0; kk < 1024; kk += 32) {
    #pragma unroll
    for (int i = 0; i < 2; ++i) {
      int r = srow + i * 64;
      const float* xp = X + grow[i] + kk + scol;
      f32x4 f0 = *(const f32x4*)(xp);
      f32x4 f1 = *(const f32x4*)(xp + 4);
      bf16x8 av;
      av[0] = (bf16)f0[0]; av[1] = (bf16)f0[1]; av[2] = (bf16)f0[2]; av[3] = (bf16)f0[3];
      av[4] = (bf16)f1[0]; av[5] = (bf16)f1[1]; av[6] = (bf16)f1[2]; av[7] = (bf16)f1[3];
      uint4 bv = *(const uint4*)(Wt + (size_t)(n0 + r) * 1024 + kk + scol);
      *(bf16x8*)(sA + r * 40 + scol) = av;
      *(uint4*)(sB + r * 40 + scol) = bv;
    }
    __syncthreads();
    bf16x8 aF[4], bF[4];
    #pragma unroll
    for (int mt = 0; mt < 4; ++mt)
      aF[mt] = *(const bf16x8*)(sA + (wm + mt * 16 + l16) * 40 + quad * 8);
    #pragma unroll
    for (int nt = 0; nt < 4; ++nt)
      bF[nt] = *(const bf16x8*)(sB + (wn + nt * 16 + l16) * 40 + quad * 8);
    #pragma unroll
    for (int mt = 0; mt < 4; ++mt)
      #pragma unroll
      for (int nt = 0; nt < 4; ++nt)
        acc[mt][nt] = MFMA16x16x32(aF[mt], bF[nt], acc[mt][nt]);
    __syncthreads();
  }

  #pragma unroll
  for (int mt = 0; mt < 4; ++mt) {
    #pragma unroll
    for (int r = 0; r < 4; ++r) {
      unsigned lr = (unsigned)(m0 + wm + mt * 16 + quad * 4 + r);
      unsigned b = lr / TC_;
      unsigned tt = lr - b * TC_;
      #pragma unroll
      for (int nt = 0; nt < 4; ++nt) {
        int n = n0 + wn + nt * 16 + l16;
        int g = n >> 10;
        int hh = n & 1023;
        XZc[((size_t)(tt * 4 + g) * B_ + b) * H_ + hh] = (bf16)acc[mt][nt][r];
      }
    }
  }
}

// ------------- one recurrence step: Z = xz_t + h_prev @ U, then gate -------------
// grid (H/32, B/32), 256 thr. wave w computes gate w's 32x32 tile; Z via LDS.
__global__ __launch_bounds__(256) void step_kernel(
    int tt,
    const bf16* __restrict__ XZc,    // (TC,4,B,H) bf16
    const bf16* __restrict__ Ut,     // (4096,1024): row n=g*1024+h, col k
    const float* __restrict__ bias,  // (4,H)
    const bf16* __restrict__ hprev,  // (B,H) bf16 = hseq slot t
    bf16* __restrict__ hnext,        // (B,H) bf16 = hseq slot t+1
    float* __restrict__ cst) {       // (B,H) fp32, updated in place
  __shared__ bf16 sA[32 * 72];       // BK=64, +8 pad: 144B stride, 16B-aligned
  __shared__ bf16 sB[4][32 * 72];
  __shared__ float sZ[4][32 * 32];

  const int tid = threadIdx.x;
  const int lane = tid & 63;
  const int w = tid >> 6;  // gate id
  const int l16 = lane & 15;
  const int quad = lane >> 4;
  const int bm0 = blockIdx.y * 32;
  const int hn0 = blockIdx.x * 32;

  const int srow = tid >> 3;       // 0..31
  const int scol = (tid & 7) * 8;  // 0..56

  f32x4 acc[2][2] = {};

  for (int kk = 0; kk < 1024; kk += 64) {
    uint4 av = *(const uint4*)(hprev + (size_t)(bm0 + srow) * 1024 + kk + scol);
    uint4 bv[4];
    #pragma unroll
    for (int gg = 0; gg < 4; ++gg)
      bv[gg] = *(const uint4*)(Ut + (size_t)(gg * 1024 + hn0 + srow) * 1024 + kk + scol);
    *(uint4*)(sA + srow * 72 + scol) = av;
    #pragma unroll
    for (int gg = 0; gg < 4; ++gg)
      *(uint4*)(&sB[gg][srow * 72 + scol]) = bv[gg];
    __syncthreads();

    #pragma unroll
    for (int kh = 0; kh < 2; ++kh) {
      bf16x8 aF[2], bF[2];
      #pragma unroll
      for (int mt = 0; mt < 2; ++mt)
        aF[mt] = *(const bf16x8*)(sA + (mt * 16 + l16) * 72 + kh * 32 + quad * 8);
      #pragma unroll
      for (int nt = 0; nt < 2; ++nt)
        bF[nt] = *(const bf16x8*)(&sB[w][(nt * 16 + l16) * 72 + kh * 32 + quad * 8]);
      #pragma unroll
      for (int mt = 0; mt < 2; ++mt)
        #pragma unroll
        for (int nt = 0; nt < 2; ++nt)
          acc[mt][nt] = MFMA16x16x32(aF[mt], bF[nt], acc[mt][nt]);
    }
    __syncthreads();
  }

  // wave w dumps its gate's Z tile (C/D layout: row=quad*4+reg, col=l16)
  #pragma unroll
  for (int mt = 0; mt < 2; ++mt)
    #pragma unroll
    for (int nt = 0; nt < 2; ++nt)
      #pragma unroll
      for (int r = 0; r < 4; ++r)
        sZ[w][(mt * 16 + quad * 4 + r) * 32 + nt * 16 + l16] = acc[mt][nt][r];
  __syncthreads();

  // gating: thread -> row rr (b), 4 consecutive h
  const int rr = tid >> 3;
  const int cc = (tid & 7) * 4;
  const int b = bm0 + rr;
  const int h = hn0 + cc;

  f32x4 zi = *(const f32x4*)(&sZ[0][rr * 32 + cc]);
  f32x4 zf = *(const f32x4*)(&sZ[1][rr * 32 + cc]);
  f32x4 zo = *(const f32x4*)(&sZ[2][rr * 32 + cc]);
  f32x4 zc = *(const f32x4*)(&sZ[3][rr * 32 + cc]);
  bf16x4 xi = *(const bf16x4*)(XZc + ((size_t)(tt * 4 + 0) * B_ + b) * H_ + h);
  bf16x4 xf = *(const bf16x4*)(XZc + ((size_t)(tt * 4 + 1) * B_ + b) * H_ + h);
  bf16x4 xo = *(const bf16x4*)(XZc + ((size_t)(tt * 4 + 2) * B_ + b) * H_ + h);
  bf16x4 xc = *(const bf16x4*)(XZc + ((size_t)(tt * 4 + 3) * B_ + b) * H_ + h);
  f32x4 bi = *(const f32x4*)(bias + 0 * H_ + h);
  f32x4 bfv = *(const f32x4*)(bias + 1 * H_ + h);
  f32x4 bo = *(const f32x4*)(bias + 2 * H_ + h);
  f32x4 bc = *(const f32x4*)(bias + 3 * H_ + h);
  f32x4 co = *(const f32x4*)(cst + (size_t)b * H_ + h);

  f32x4 cn;
  bf16x4 hb;
  #pragma unroll
  for (int j = 0; j < 4; ++j) {
    float I  = sigmoid_f(zi[j] + (float)xi[j] + bi[j]);
    float Fg = sigmoid_f(zf[j] + (float)xf[j] + bfv[j]);
    float O  = sigmoid_f(zo[j] + (float)xo[j] + bo[j]);
    float Ct = b2bsqrt_f(zc[j] + (float)xc[j] + bc[j]);
    float c2 = Fg * co[j] + I * Ct;
    cn[j] = c2;
    hb[j] = (bf16)(O * b2bsqrt_f(c2));
  }
  *(f32x4*)(cst + (size_t)b * H_ + h) = cn;
  *(bf16x4*)(hnext + (size_t)b * H_ + h) = hb;
}

// ---------------- LayerNorm + FC(H->10), one wave per (b,t) row ----------------
__global__ __launch_bounds__(256) void ln_fc_kernel(
    const bf16* __restrict__ hseq,  // (T+1,B,H), slot t+1 holds h_t
    const float* __restrict__ lng, const float* __restrict__ lnb,
    const float* __restrict__ fcw, const float* __restrict__ fcb,
    float* __restrict__ out) {
  const int lane = threadIdx.x & 63;
  const int wv = threadIdx.x >> 6;
  const int row = blockIdx.x * 4 + wv;  // row = b*T + t
  const unsigned b = (unsigned)row / 100u;
  const unsigned t = (unsigned)row - b * 100u;
  const bf16* base = hseq + ((size_t)(t + 1) * B_ + b) * H_;

  float v[16];
  float s = 0.f, q = 0.f;
  #pragma unroll
  for (int j = 0; j < 2; ++j) {
    bf16x8 hv = *(const bf16x8*)(base + (j * 64 + lane) * 8);
    #pragma unroll
    for (int k = 0; k < 8; ++k) {
      float f = (float)hv[k];
      v[j * 8 + k] = f;
      s += f; q += f * f;
    }
  }
  #pragma unroll
  for (int off = 32; off > 0; off >>= 1) {
    s += __shfl_xor(s, off, 64);
    q += __shfl_xor(q, off, 64);
  }
  float mu = s * (1.0f / 1024.0f);
  float var = q * (1.0f / 1024.0f) - mu * mu;
  float rs = rsqrtf(var + 1e-5f);

  float la[10];
  #pragma unroll
  for (int c = 0; c < 10; ++c) la[c] = 0.f;
  #pragma unroll
  for (int j = 0; j < 2; ++j) {
    #pragma unroll
    for (int k = 0; k < 8; ++k) {
      int hh = (j * 64 + lane) * 8 + k;
      float y = (v[j * 8 + k] - mu) * rs * lng[hh] + lnb[hh];
      #pragma unroll
      for (int c = 0; c < 10; ++c) la[c] += y * fcw[hh * 10 + c];
    }
  }
  #pragma unroll
  for (int off = 32; off > 0; off >>= 1) {
    #pragma unroll
    for (int c = 0; c < 10; ++c) la[c] += __shfl_xor(la[c], off, 64);
  }
  if (lane == 0) {
    #pragma unroll
    for (int c = 0; c < 10; ++c) out[(size_t)row * 10 + c] = la[c] + fcb[c];
  }
}

extern "C" void kernel_launch(void* const* d_in, const int* in_sizes, int n_in,
                              void* d_out, int out_size, void* d_ws, size_t ws_size,
                              hipStream_t stream) {
  (void)in_sizes; (void)n_in; (void)out_size; (void)ws_size;
  const float* x    = (const float*)d_in[0];  // (B,T,F)
  const float* W    = (const float*)d_in[1];  // (4,F,H)
  const float* U    = (const float*)d_in[2];  // (4,H,H)
  const float* bias = (const float*)d_in[3];  // (4,H)
  const float* lng  = (const float*)d_in[4];
  const float* lnb  = (const float*)d_in[5];
  const float* fcw  = (const float*)d_in[6];  // (H,C)
  const float* fcb  = (const float*)d_in[7];
  float* out = (float*)d_out;

  char* ws = (char*)d_ws;
  size_t off = 0;
  bf16* Wt   = (bf16*)(ws + off); off += (size_t)4 * F_ * H_ * 2;           //   8,388,608
  bf16* Ut   = (bf16*)(ws + off); off += (size_t)4 * H_ * H_ * 2;           //   8,388,608
  bf16* XZc  = (bf16*)(ws + off); off += (size_t)TC_ * 4 * B_ * H_ * 2;     //  41,943,040
  bf16* hseq = (bf16*)(ws + off); off += (size_t)(T_ + 1) * B_ * H_ * 2;    // 105,906,176
  float* cst = (float*)(ws + off); off += (size_t)B_ * H_ * 4;              //   2,097,152
  // total ~159 MB

  zero_init<<<(B_ * H_ + 255) / 256, 256, 0, stream>>>(hseq, cst, B_ * H_);
  tr_kernel<<<dim3(32, 32, 4), 256, 0, stream>>>(W, Wt);
  tr_kernel<<<dim3(32, 32, 4), 256, 0, stream>>>(U, Ut);

  for (int chunk = 0; chunk < T_ / TC_; ++chunk) {
    int t0 = chunk * TC_;
    gemm_xz<<<dim3(32, (B_ * TC_) / 128), 256, 0, stream>>>(x, Wt, XZc, t0);
    for (int tt = 0; tt < TC_; ++tt) {
      int t = t0 + tt;
      step_kernel<<<dim3(H_ / 32, B_ / 32), 256, 0, stream>>>(
          tt, XZc, Ut, bias,
          hseq + (size_t)t * B_ * H_,
          hseq + (size_t)(t + 1) * B_ * H_,
          cst);
    }
  }

  ln_fc_kernel<<<(B_ * T_) / 4, 256, 0, stream>>>(hseq, lng, lnb, fcw, fcb, out);
}

// Round 3
// 2448.394 us; speedup vs baseline: 1.1541x; 1.1541x over previous
//
#include <hip/hip_runtime.h>
#include <stdint.h>

typedef __bf16 bf16;
typedef __bf16 bf16x4 __attribute__((ext_vector_type(4)));
typedef __bf16 bf16x8 __attribute__((ext_vector_type(8)));
typedef float f32x4 __attribute__((ext_vector_type(4)));

#define MFMA16x16x32(A, B, C) __builtin_amdgcn_mfma_f32_16x16x32_bf16((A), (B), (C), 0, 0, 0)

#define B_ 512
#define T_ 100
#define F_ 1024
#define H_ 1024
#define TC_ 10  // T-chunk for XZ staging

__device__ __forceinline__ float sigmoid_f(float x) { return 1.0f / (1.0f + __expf(-x)); }
__device__ __forceinline__ float b2bsqrt_f(float x) {
  float s = sqrtf(1.0f + fabsf(x)) - 1.0f;
  return x >= 0.0f ? s : -s;  // x==0 -> s==0, matches sign(0)=0
}

// async global->LDS, 16B per lane; LDS dest = wave-uniform base + lane*16
__device__ __forceinline__ void glds16(const void* g, void* l) {
  __builtin_amdgcn_global_load_lds((const __attribute__((address_space(1))) void*)g,
                                   (__attribute__((address_space(3))) void*)l, 16, 0, 0);
}

// ---------------- zero-init h slot 0 and c state (capture-safe) ----------------
__global__ __launch_bounds__(256) void zero_init(bf16* __restrict__ h0,
                                                 float* __restrict__ c0, int n) {
  int i = blockIdx.x * blockDim.x + threadIdx.x;
  if (i < n) { h0[i] = (bf16)0.0f; c0[i] = 0.0f; }
}

// ---------- transpose per gate: fp32 (1024 x 1024) -> bf16 transposed ----------
__global__ __launch_bounds__(256) void tr_kernel(const float* __restrict__ src,
                                                 bf16* __restrict__ dst) {
  __shared__ float tile[32][33];
  int g = blockIdx.z;
  int c0 = blockIdx.x * 32;
  int r0 = blockIdx.y * 32;
  const float* s = src + (size_t)g * 1024 * 1024;
  bf16* d = dst + (size_t)g * 1024 * 1024;
  int tx = threadIdx.x & 31, ty = threadIdx.x >> 5;
  #pragma unroll
  for (int i = 0; i < 32; i += 8)
    tile[ty + i][tx] = s[(size_t)(r0 + ty + i) * 1024 + c0 + tx];
  __syncthreads();
  #pragma unroll
  for (int i = 0; i < 32; i += 8)
    d[(size_t)(c0 + ty + i) * 1024 + r0 + tx] = (bf16)tile[tx][ty + i];
}

// ---------- convert x chunk fp32 -> bf16: xbf[(b*TC+tt), f] = x[b, t0+tt, f] ----------
__global__ __launch_bounds__(256) void convx(const float* __restrict__ x,
                                             bf16* __restrict__ xbf, int t0) {
  int lr = blockIdx.x * 4 + (threadIdx.x >> 6);
  int lane = threadIdx.x & 63;
  unsigned b = (unsigned)lr / 10u;
  unsigned tt = (unsigned)lr - b * 10u;
  const float* src = x + (size_t)(b * 100u + (unsigned)t0 + tt) * 1024;
  bf16* dst = xbf + (size_t)lr * 1024;
  #pragma unroll
  for (int j = 0; j < 4; ++j) {
    f32x4 f = *(const f32x4*)(src + (j * 64 + lane) * 4);
    bf16x4 o;
    o[0] = (bf16)f[0]; o[1] = (bf16)f[1]; o[2] = (bf16)f[2]; o[3] = (bf16)f[3];
    *(bf16x4*)(dst + (j * 64 + lane) * 4) = o;
  }
}

// ---------- prep FC: Bt[c][h] = ln_g[h]*fcw[h,c] (c<10), ones (c==10), 0 else;
//            SA[c] = sum_h Bt[c][h], SA[16+c] = sum_h ln_b[h]*fcw[h,c] + fcb[c] ----------
__global__ __launch_bounds__(256) void prep_fc(const float* __restrict__ lng,
                                               const float* __restrict__ lnb,
                                               const float* __restrict__ fcw,
                                               const float* __restrict__ fcb,
                                               bf16* __restrict__ Bt,
                                               float* __restrict__ SA) {
  __shared__ float red[2][256];
  int c = blockIdx.x;  // 0..15
  int tid = threadIdx.x;
  float pS = 0.f, pA = 0.f;
  #pragma unroll
  for (int j = 0; j < 4; ++j) {
    int h = j * 256 + tid;
    float v;
    if (c < 10) {
      float wv = fcw[h * 10 + c];
      v = lng[h] * wv;
      pS += v;
      pA += lnb[h] * wv;
    } else {
      v = (c == 10) ? 1.0f : 0.0f;
    }
    Bt[c * 1024 + h] = (bf16)v;
  }
  if (c < 10) {
    red[0][tid] = pS; red[1][tid] = pA;
    __syncthreads();
    for (int s = 128; s > 0; s >>= 1) {
      if (tid < s) { red[0][tid] += red[0][tid + s]; red[1][tid] += red[1][tid + s]; }
      __syncthreads();
    }
    if (tid == 0) { SA[c] = red[0][0]; SA[16 + c] = red[1][0] + fcb[c]; }
  }
}

// ---------------- xz chunk GEMM (m97-style): XZc = xbf @ Wt^T ----------------
// xbf (5120,1024) bf16; Wt (4096,1024) bf16 row n=g*1024+h. Out XZc bf16 (TC,4,B,H).
__global__ __launch_bounds__(256) void gemm_xz(const bf16* __restrict__ X,
                                               const bf16* __restrict__ Wt,
                                               bf16* __restrict__ XZc) {
  __shared__ bf16 sA[128 * 32];
  __shared__ bf16 sB[128 * 32];
  const int tid = threadIdx.x;
  const int lane = tid & 63;
  const int w = tid >> 6;
  const int l16 = lane & 15;
  const int quad = lane >> 4;
  const int m0 = blockIdx.y * 128;
  const int n0 = blockIdx.x * 128;
  const int wm = (w >> 1) * 64;
  const int wn = (w & 1) * 64;
  const int rA = lane >> 2;                 // 0..15 within an issue
  const int gch = (lane & 3) ^ (rA & 3);    // XOR-swizzled global 16B chunk

  f32x4 acc[4][4] = {};

  for (int kk = 0; kk < 1024; kk += 32) {
    #pragma unroll
    for (int j = 0; j < 2; ++j) {
      int r0 = (w * 2 + j) * 16;
      int r = r0 + rA;
      glds16(X + (size_t)(m0 + r) * 1024 + kk + gch * 8, sA + r0 * 32);
      glds16(Wt + (size_t)(n0 + r) * 1024 + kk + gch * 8, sB + r0 * 32);
    }
    __syncthreads();
    bf16x8 aF[4], bF[4];
    const int slot = quad ^ (l16 & 3);
    #pragma unroll
    for (int mt = 0; mt < 4; ++mt)
      aF[mt] = *(const bf16x8*)(sA + (wm + mt * 16 + l16) * 32 + slot * 8);
    #pragma unroll
    for (int nt = 0; nt < 4; ++nt)
      bF[nt] = *(const bf16x8*)(sB + (wn + nt * 16 + l16) * 32 + slot * 8);
    #pragma unroll
    for (int mt = 0; mt < 4; ++mt)
      #pragma unroll
      for (int nt = 0; nt < 4; ++nt)
        acc[mt][nt] = MFMA16x16x32(aF[mt], bF[nt], acc[mt][nt]);
    __syncthreads();
  }

  #pragma unroll
  for (int mt = 0; mt < 4; ++mt) {
    #pragma unroll
    for (int r = 0; r < 4; ++r) {
      unsigned lr = (unsigned)(m0 + wm + mt * 16 + quad * 4 + r);
      unsigned b = lr / 10u;
      unsigned tt = lr - b * 10u;
      #pragma unroll
      for (int nt = 0; nt < 4; ++nt) {
        int n = n0 + wn + nt * 16 + l16;
        int g = n >> 10;
        int hh = n & 1023;
        XZc[((size_t)(tt * 4 + g) * B_ + b) * H_ + hh] = (bf16)acc[mt][nt][r];
      }
    }
  }
}

// ------------- recurrence step: Z = xz_t + h_prev @ U, gate; 64b x 16h x 4g -------------
// grid (64, 8). Wave w = gate w (64x16 tile). Natural linearization puts the 8 b-tiles
// sharing an n-tile on one XCD (L%8 == blockIdx.x%8) -> Ut slice L2-resident.
__global__ __launch_bounds__(256) void step_kernel(
    int tt,
    const bf16* __restrict__ XZc,    // (TC,4,B,H) bf16
    const bf16* __restrict__ Ut,     // (4096,1024): row n=g*1024+h, col k
    const float* __restrict__ bias,  // (4,H)
    const bf16* __restrict__ hprev,  // (B,H) bf16 = hseq slot t
    bf16* __restrict__ hnext,        // (B,H) bf16 = hseq slot t+1
    float* __restrict__ cst) {       // (B,H) fp32, in place
  __shared__ bf16 sA[64 * 64];
  __shared__ bf16 sB[64 * 64];       // row R = g*16+rr
  __shared__ float sZ[4][64 * 20];   // stride 20 floats: 16B-aligned, 2-way banks

  const int tid = threadIdx.x;
  const int lane = tid & 63;
  const int w = tid >> 6;  // gate id
  const int l16 = lane & 15;
  const int quad = lane >> 4;
  const int hn0 = blockIdx.x * 16;
  const int bm0 = blockIdx.y * 64;
  const int rL = lane >> 3;                 // 0..7 within an issue
  const int gch = (lane & 7) ^ rL;          // XOR-swizzled chunk

  f32x4 acc[4] = {};

  for (int kk = 0; kk < 1024; kk += 64) {
    #pragma unroll
    for (int j = 0; j < 2; ++j) {
      int r0 = (w * 2 + j) * 8;
      int r = r0 + rL;
      glds16(hprev + (size_t)(bm0 + r) * 1024 + kk + gch * 8, sA + r0 * 64);
      int g = r >> 4, rr = r & 15;
      glds16(Ut + (size_t)((g << 10) + hn0 + rr) * 1024 + kk + gch * 8, sB + r0 * 64);
    }
    __syncthreads();
    #pragma unroll
    for (int kh = 0; kh < 2; ++kh) {
      const int slot = (kh * 4 + quad) ^ (l16 & 7);
      bf16x8 bF = *(const bf16x8*)(sB + (w * 16 + l16) * 64 + slot * 8);
      #pragma unroll
      for (int mt = 0; mt < 4; ++mt) {
        bf16x8 aF = *(const bf16x8*)(sA + (mt * 16 + l16) * 64 + slot * 8);
        acc[mt] = MFMA16x16x32(aF, bF, acc[mt]);
      }
    }
    __syncthreads();
  }

  // dump Z (C/D layout row=quad*4+r, col=l16)
  #pragma unroll
  for (int mt = 0; mt < 4; ++mt)
    #pragma unroll
    for (int r = 0; r < 4; ++r)
      sZ[w][(mt * 16 + quad * 4 + r) * 20 + l16] = acc[mt][r];
  __syncthreads();

  // gate: thread -> b-row rr (0..63), 4 consecutive h
  const int rr = tid >> 2;
  const int cc = (tid & 3) * 4;
  const int b = bm0 + rr;
  const int h = hn0 + cc;

  f32x4 z[4]; bf16x4 xz[4]; f32x4 bs[4];
  #pragma unroll
  for (int g = 0; g < 4; ++g) {
    z[g] = *(const f32x4*)(&sZ[g][rr * 20 + cc]);
    xz[g] = *(const bf16x4*)(XZc + ((size_t)(tt * 4 + g) * B_ + b) * H_ + h);
    bs[g] = *(const f32x4*)(bias + g * 1024 + h);
  }
  f32x4 co = *(const f32x4*)(cst + (size_t)b * H_ + h);

  f32x4 cn; bf16x4 hb;
  #pragma unroll
  for (int jj = 0; jj < 4; ++jj) {
    float I  = sigmoid_f(z[0][jj] + (float)xz[0][jj] + bs[0][jj]);
    float Fg = sigmoid_f(z[1][jj] + (float)xz[1][jj] + bs[1][jj]);
    float O  = sigmoid_f(z[2][jj] + (float)xz[2][jj] + bs[2][jj]);
    float Ct = b2bsqrt_f(z[3][jj] + (float)xz[3][jj] + bs[3][jj]);
    float c2 = Fg * co[jj] + I * Ct;
    cn[jj] = c2;
    hb[jj] = (bf16)(O * b2bsqrt_f(c2));
  }
  *(f32x4*)(cst + (size_t)b * H_ + h) = cn;
  *(bf16x4*)(hnext + (size_t)b * H_ + h) = hb;
}

// ------------- LN+FC as MFMA GEMM: (51200 x 1024) @ (1024 x 16) -------------
// hseq1 = hseq + B*H (slot 1). Row rg = t*512 + b. Col 0..9 = dot(h, v_c), col 10 = sum(h).
// sumsq accumulated in VALU from A-fragments. Finalize per-row affine.
__global__ __launch_bounds__(256) void ln_fc_kernel(
    const bf16* __restrict__ hseq1, const bf16* __restrict__ Bt,
    const float* __restrict__ SA, float* __restrict__ out) {
  __shared__ bf16 sA[64 * 64];
  __shared__ bf16 sBt[16 * 1040];   // +16B/row pad (plain-staged, so padding is OK)
  __shared__ float sLg[4][16 * 17];
  __shared__ float sSq[4][16];
  const int tid = threadIdx.x;
  const int lane = tid & 63;
  const int w = tid >> 6;
  const int l16 = lane & 15;
  const int quad = lane >> 4;
  const int m0 = blockIdx.x * 64;
  const int rL = lane >> 3;
  const int gch = (lane & 7) ^ rL;

  // stage whole Bt (16x1024) into padded LDS
  #pragma unroll
  for (int i = 0; i < 8; ++i) {
    int ch = tid + i * 256;
    int n = ch >> 7, k8 = ch & 127;
    *(bf16x8*)(sBt + n * 1040 + k8 * 8) = *(const bf16x8*)(Bt + n * 1024 + k8 * 8);
  }

  f32x4 acc = {};
  float sq = 0.f;

  for (int kk = 0; kk < 1024; kk += 64) {
    #pragma unroll
    for (int j = 0; j < 2; ++j) {
      int r0 = (w * 2 + j) * 8;
      int r = r0 + rL;
      glds16(hseq1 + (size_t)(m0 + r) * 1024 + kk + gch * 8, sA + r0 * 64);
    }
    __syncthreads();
    #pragma unroll
    for (int kh = 0; kh < 2; ++kh) {
      const int slot = (kh * 4 + quad) ^ (l16 & 7);
      bf16x8 aF = *(const bf16x8*)(sA + (w * 16 + l16) * 64 + slot * 8);
      bf16x8 bF = *(const bf16x8*)(sBt + l16 * 1040 + kk + kh * 32 + quad * 8);
      acc = MFMA16x16x32(aF, bF, acc);
      #pragma unroll
      for (int e = 0; e < 8; ++e) { float f = (float)aF[e]; sq += f * f; }
    }
    __syncthreads();
  }

  // reduce sq over quads (lanes sharing l16): each lane covered k-slices of row l16
  sq += __shfl_xor(sq, 16, 64);
  sq += __shfl_xor(sq, 32, 64);

  #pragma unroll
  for (int r = 0; r < 4; ++r)
    sLg[w][(quad * 4 + r) * 17 + l16] = acc[r];
  if (quad == 0) sSq[w][l16] = sq;
  __syncthreads();

  if (lane < 16) {
    int row = lane;
    float sum = sLg[w][row * 17 + 10];
    float ssq = sSq[w][row];
    float mu = sum * (1.0f / 1024.0f);
    float var = ssq * (1.0f / 1024.0f) - mu * mu;
    float rs = rsqrtf(var + 1e-5f);
    int rg = m0 + w * 16 + row;
    int t = rg >> 9, b = rg & 511;
    float* op = out + ((size_t)b * 100 + t) * 10;
    #pragma unroll
    for (int c = 0; c < 10; ++c)
      op[c] = rs * (sLg[w][row * 17 + c] - mu * SA[c]) + SA[16 + c];
  }
}

extern "C" void kernel_launch(void* const* d_in, const int* in_sizes, int n_in,
                              void* d_out, int out_size, void* d_ws, size_t ws_size,
                              hipStream_t stream) {
  (void)in_sizes; (void)n_in; (void)out_size; (void)ws_size;
  const float* x    = (const float*)d_in[0];  // (B,T,F)
  const float* W    = (const float*)d_in[1];  // (4,F,H)
  const float* U    = (const float*)d_in[2];  // (4,H,H)
  const float* bias = (const float*)d_in[3];  // (4,H)
  const float* lng  = (const float*)d_in[4];
  const float* lnb  = (const float*)d_in[5];
  const float* fcw  = (const float*)d_in[6];  // (H,10)
  const float* fcb  = (const float*)d_in[7];
  float* out = (float*)d_out;

  char* ws = (char*)d_ws;
  size_t off = 0;
  bf16* Wt   = (bf16*)(ws + off); off += (size_t)4 * F_ * H_ * 2;         //   8.4 MB
  bf16* Ut   = (bf16*)(ws + off); off += (size_t)4 * H_ * H_ * 2;         //   8.4 MB
  bf16* XZc  = (bf16*)(ws + off); off += (size_t)TC_ * 4 * B_ * H_ * 2;   //  41.9 MB
  bf16* hseq = (bf16*)(ws + off); off += (size_t)(T_ + 1) * B_ * H_ * 2;  // 105.9 MB
  float* cst = (float*)(ws + off); off += (size_t)B_ * H_ * 4;            //   2.1 MB
  bf16* xbf  = (bf16*)(ws + off); off += (size_t)B_ * TC_ * F_ * 2;       //  10.5 MB
  bf16* Bt   = (bf16*)(ws + off); off += (size_t)16 * H_ * 2;             //  32 KB
  float* SA  = (float*)(ws + off); off += 32 * 4;
  // total ~177 MB

  zero_init<<<(B_ * H_ + 255) / 256, 256, 0, stream>>>(hseq, cst, B_ * H_);
  tr_kernel<<<dim3(32, 32, 4), 256, 0, stream>>>(W, Wt);
  tr_kernel<<<dim3(32, 32, 4), 256, 0, stream>>>(U, Ut);
  prep_fc<<<16, 256, 0, stream>>>(lng, lnb, fcw, fcb, Bt, SA);

  for (int chunk = 0; chunk < T_ / TC_; ++chunk) {
    int t0 = chunk * TC_;
    convx<<<(B_ * TC_) / 4, 256, 0, stream>>>(x, xbf, t0);
    gemm_xz<<<dim3(32, (B_ * TC_) / 128), 256, 0, stream>>>(xbf, Wt, XZc);
    for (int tt = 0; tt < TC_; ++tt) {
      int t = t0 + tt;
      step_kernel<<<dim3(H_ / 16, B_ / 64), 256, 0, stream>>>(
          tt, XZc, Ut, bias,
          hseq + (size_t)t * B_ * H_,
          hseq + (size_t)(t + 1) * B_ * H_,
          cst);
    }
  }

  ln_fc_kernel<<<(B_ * T_) / 64, 256, 0, stream>>>(hseq + (size_t)B_ * H_, Bt, SA, out);
}